// Round 8
// baseline (750.654 us; speedup 1.0000x reference)
//
#include <hip/hip_runtime.h>

typedef short s16x4 __attribute__((ext_vector_type(4)));
typedef short s16x8 __attribute__((ext_vector_type(8)));
typedef float f32x16 __attribute__((ext_vector_type(16)));
typedef float f32x4 __attribute__((ext_vector_type(4)));

__device__ __forceinline__ float bf2f(short s) {
  unsigned int u = ((unsigned int)(unsigned short)s) << 16;
  return __builtin_bit_cast(float, u);
}
__device__ __forceinline__ short f2bf(float f) {
  unsigned int u = __builtin_bit_cast(unsigned int, f);
  u += 0x7fffu + ((u >> 16) & 1u);   // RNE
  return (short)(u >> 16);
}

#define GEPS 1e-20f

// ---------------- dtype detector (unchanged, proven) ----------------
__global__ __launch_bounds__(256) void k_detect(const short* __restrict__ cb,
                                                int* __restrict__ flag) {
  __shared__ int cnt[256];
  int c = 0;
#pragma unroll
  for (int i = 0; i < 64; ++i) {
    unsigned short v = (unsigned short)cb[threadIdx.x * 64 + i];
    if (((v >> 7) & 0xFF) >= 0x90) ++c;
  }
  cnt[threadIdx.x] = c;
  __syncthreads();
  for (int s = 128; s; s >>= 1) {
    if (threadIdx.x < (unsigned)s) cnt[threadIdx.x] += cnt[threadIdx.x + s];
    __syncthreads();
  }
  if (threadIdx.x == 0) flag[0] = (cnt[0] > 512) ? 1 : 0;
}

// ---------------- codebook prep (unchanged, proven) ----------------
__device__ __forceinline__ int fragidx(int n, int k) {
  return ((((n >> 5) * 64 + (k >> 4)) * 2 + ((k >> 3) & 1)) << 8) + ((n & 31) << 3) + (k & 7);
}

__global__ __launch_bounds__(256) void k_prep(const void* __restrict__ cb,
                                              short* __restrict__ CBhiX,
                                              short* __restrict__ CBloX,
                                              short* __restrict__ CTX,
                                              const int* __restrict__ flag) {
  const int f32m = *flag;
  const int idx = blockIdx.x * 256 + threadIdx.x;   // 1M elements
  const int v = idx >> 10, d = idx & 1023;
  float val;
  if (f32m) val = ((const float*)cb)[idx];
  else      val = bf2f(((const short*)cb)[idx]);
  short hi = f2bf(val);
  short lo = f2bf(val - bf2f(hi));
  CBhiX[fragidx(v, d)] = hi;
  CBloX[fragidx(v, d)] = lo;
  CTX[fragidx(d, v)]   = hi;
}

// ---------------- fused GVQ v6 ----------------
// 1024 thr = 16 waves, M=64 rows/block (grid 512), 1 block/CU, 4 waves/SIMD.
// v6 vs v5: wave tile re-shaped 64x64 -> 32x128. Wave w: wc=w&7 owns cols
// [wc*128,(wc+1)*128) (nt 0..3), wr=w>>3 owns rows [wr*32,wr*32+32).
// Wave PAIRS (wr=0/1, same wc) read IDENTICAL B-fragments -> L1/MSHR merge
// halves the L2 codebook stream (was ~107K cyc/block, co-equal with MFMA);
// per-wave A/P ds_reads halve -> bank conflicts back to v4 level.
// acc = 4 x f32x16 = 64 AGPR (same budget), MFMA count/wave unchanged.
__global__ __launch_bounds__(1024, 4) void k_gvq(
    const void* __restrict__ Xv,
    const short* __restrict__ CBhiX,
    const short* __restrict__ CBloX,
    const short* __restrict__ CTX,
    const void* __restrict__ Gv,
    void* __restrict__ outv,
    const int* __restrict__ flag) {
  // 128 KB: P panels [16][64][64] shorts (panel p at p*4096, p = v-col/64).
  // GEMM1 staging overlays panels 0..3: buf b at b*8192 (hi +0, lo +4096).
  __shared__ __attribute__((aligned(16))) short AP[65536];
  __shared__ float rmaxL[8][64];
  __shared__ float rsumL[8][64];
  __shared__ float rowMax[64];
  __shared__ float rowInv[64];

  const int f32m = *flag;
  const int tid = threadIdx.x;
  const int l  = tid & 63;
  const int w  = tid >> 6;
  const int wc = w & 7;             // col group: cols [wc*128, wc*128+128)
  const int wr = w >> 3;            // row half: rows [wr*32, wr*32+32)
  const int ln = l & 31;
  const int h  = l >> 5;
  const int sw = ln & 7;            // (row & 7) for all A-row reads
  const int r0 = blockIdx.x * 64;

  // staging map: 1024 threads <-> 64 rows x 16 quarter-chunks (4 elems)
  const int sr = tid >> 4;
  const int scq = tid & 15;
  const int so4 = sr * 64 + ((((scq >> 1) ^ (sr & 7))) << 3) + ((scq & 1) << 2);

  f32x16 acc[4];
#pragma unroll
  for (int nt = 0; nt < 4; ++nt)
#pragma unroll
    for (int i = 0; i < 16; ++i) acc[nt][i] = 0.0f;

  const short* bhb = CBhiX + (wc * 4) * 32768 + h * 256 + ln * 8;
  const short* blb = CBloX + (wc * 4) * 32768 + h * 256 + ln * 8;
  const int abase = (wr * 32 + ln) * 64;   // this wave's 32 A-rows

  // ---- GEMM1, K-tiled BK=64, double-buffered ----
  if (f32m) {
    {
      const float* xp = (const float*)Xv + (r0 + sr) * 1024 + scq * 4;
      f32x4 a = __builtin_nontemporal_load((const f32x4*)xp);
      s16x4 hi4, lo4;
#pragma unroll
      for (int j = 0; j < 4; ++j) {
        hi4[j] = f2bf(a[j]);
        lo4[j] = f2bf(a[j] - bf2f(hi4[j]));
      }
      *(s16x4*)&AP[so4] = hi4;
      *(s16x4*)&AP[4096 + so4] = lo4;
    }
    __syncthreads();
    for (int t = 0; t < 16; ++t) {
      const int buf = t & 1;
      f32x4 xa;
      if (t < 15) {   // issue next tile's loads before compute (T14)
        const float* xp = (const float*)Xv + (r0 + sr) * 1024 + (t + 1) * 64 + scq * 4;
        xa = __builtin_nontemporal_load((const f32x4*)xp);
      }
      const short* Ah = &AP[buf * 8192] + abase;
      const short* Al = Ah + 4096;
#pragma unroll
      for (int ks = 0; ks < 4; ++ks) {
        const int ao = ((2 * ks + h) ^ sw) << 3;
        s16x8 ah = *(const s16x8*)(Ah + ao);
        s16x8 al = *(const s16x8*)(Al + ao);
#pragma unroll
        for (int nt = 0; nt < 4; ++nt) {
          const int bo = nt * 32768 + (t * 4 + ks) * 512;
          s16x8 bh = *(const s16x8*)(bhb + bo);
          s16x8 bl = *(const s16x8*)(blb + bo);
          acc[nt] = __builtin_amdgcn_mfma_f32_32x32x16_bf16(ah, bh, acc[nt], 0, 0, 0);
          acc[nt] = __builtin_amdgcn_mfma_f32_32x32x16_bf16(al, bh, acc[nt], 0, 0, 0);
          acc[nt] = __builtin_amdgcn_mfma_f32_32x32x16_bf16(ah, bl, acc[nt], 0, 0, 0);
        }
      }
      if (t < 15) {
        s16x4 hi4, lo4;
#pragma unroll
        for (int j = 0; j < 4; ++j) {
          hi4[j] = f2bf(xa[j]);
          lo4[j] = f2bf(xa[j] - bf2f(hi4[j]));
        }
        short* d = &AP[(buf ^ 1) * 8192] + so4;
        *(s16x4*)d = hi4;
        *(s16x4*)(d + 4096) = lo4;
      }
      __syncthreads();
    }
  } else {
    // bf16 input: Xlo = 0 and CBlo = 0 -> single-MFMA inner loop, hi only
    {
      s16x4 hi4 = __builtin_nontemporal_load(
          (const s16x4*)((const short*)Xv + (r0 + sr) * 1024 + scq * 4));
      *(s16x4*)&AP[so4] = hi4;
    }
    __syncthreads();
    for (int t = 0; t < 16; ++t) {
      const int buf = t & 1;
      s16x4 xs;
      if (t < 15) {
        xs = __builtin_nontemporal_load(
            (const s16x4*)((const short*)Xv + (r0 + sr) * 1024 + (t + 1) * 64 + scq * 4));
      }
      const short* Ah = &AP[buf * 8192] + abase;
#pragma unroll
      for (int ks = 0; ks < 4; ++ks) {
        const int ao = ((2 * ks + h) ^ sw) << 3;
        s16x8 ah = *(const s16x8*)(Ah + ao);
#pragma unroll
        for (int nt = 0; nt < 4; ++nt) {
          const int bo = nt * 32768 + (t * 4 + ks) * 512;
          s16x8 bh = *(const s16x8*)(bhb + bo);
          acc[nt] = __builtin_amdgcn_mfma_f32_32x32x16_bf16(ah, bh, acc[nt], 0, 0, 0);
        }
      }
      if (t < 15) {
        *(s16x4*)(&AP[(buf ^ 1) * 8192] + so4) = xs;
      }
      __syncthreads();
    }
  }

  // ---- gumbel + /T; per-row max. C/D: row=(r&3)+8*(r>>2)+4h, col=ln ----
  float pmax[16];
#pragma unroll
  for (int r = 0; r < 16; ++r) pmax[r] = -3.0e38f;
#pragma unroll
  for (int nt = 0; nt < 4; ++nt) {
    const int c = wc * 128 + nt * 32 + ln;
    const int rb = r0 + wr * 32;
    float ur[16];
    if (f32m) {
      const float* gp = (const float*)Gv + rb * 1024 + c;
#pragma unroll
      for (int r = 0; r < 16; ++r) {
        const int rho = (r & 3) + 8 * (r >> 2) + 4 * h;
        ur[r] = __builtin_nontemporal_load(gp + rho * 1024);
      }
    } else {
      const short* gp = (const short*)Gv + rb * 1024 + c;
#pragma unroll
      for (int r = 0; r < 16; ++r) {
        const int rho = (r & 3) + 8 * (r >> 2) + 4 * h;
        ur[r] = bf2f(__builtin_nontemporal_load(gp + rho * 1024));
      }
    }
#pragma unroll
    for (int r = 0; r < 16; ++r) {
      float gvn = -__logf(-__logf(ur[r] + GEPS) + GEPS);
      float y = (acc[nt][r] + gvn) * 2.0f;
      acc[nt][r] = y;
      pmax[r] = fmaxf(pmax[r], y);
    }
  }
#pragma unroll
  for (int off = 16; off; off >>= 1)
#pragma unroll
    for (int r = 0; r < 16; ++r)
      pmax[r] = fmaxf(pmax[r], __shfl_xor(pmax[r], off, 64));
  if (ln == 0) {
#pragma unroll
    for (int r = 0; r < 16; ++r)
      rmaxL[wc][wr * 32 + (r & 3) + 8 * (r >> 2) + 4 * h] = pmax[r];
  }
  __syncthreads();
  if (tid < 64) {
    float m = rmaxL[0][tid];
#pragma unroll
    for (int j = 1; j < 8; ++j) m = fmaxf(m, rmaxL[j][tid]);
    rowMax[tid] = m;
  }
  __syncthreads();

  // ---- exp + per-row sum ----
  float psum[16];
#pragma unroll
  for (int r = 0; r < 16; ++r) {
    const int rloc = wr * 32 + (r & 3) + 8 * (r >> 2) + 4 * h;
    float rm = rowMax[rloc];
    float s = 0.0f;
#pragma unroll
    for (int nt = 0; nt < 4; ++nt) {
      float e = __expf(acc[nt][r] - rm);
      acc[nt][r] = e;
      s += e;
    }
    psum[r] = s;
  }
#pragma unroll
  for (int off = 16; off; off >>= 1)
#pragma unroll
    for (int r = 0; r < 16; ++r)
      psum[r] += __shfl_xor(psum[r], off, 64);
  if (ln == 0) {
#pragma unroll
    for (int r = 0; r < 16; ++r)
      rsumL[wc][wr * 32 + (r & 3) + 8 * (r >> 2) + 4 * h] = psum[r];
  }
  __syncthreads();
  if (tid < 64) {
    float s = rsumL[0][tid];
#pragma unroll
    for (int j = 1; j < 8; ++j) s += rsumL[j][tid];
    rowInv[tid] = 1.0f / s;
  }
  __syncthreads();

  // ---- normalize: store soft_one_hot (nt), write P into LDS panels ----
  float* outQf = (float*)outv;
  float* outPf = outQf + 33554432;
  short* outQs = (short*)outv;
  short* outPs = outQs + 33554432;

#pragma unroll
  for (int nt = 0; nt < 4; ++nt) {
    const int c = wc * 128 + nt * 32 + ln;
    const int panel = c >> 6;          // v-col panel, 0..15
    const int cl = c & 63;
    const int g = cl >> 3, cs = cl & 7;
    short* Pb = &AP[panel * 4096];
#pragma unroll
    for (int r = 0; r < 16; ++r) {
      const int rloc = wr * 32 + (r & 3) + 8 * (r >> 2) + 4 * h;
      const int row = r0 + rloc;
      float p = acc[nt][r] * rowInv[rloc];
      short pb = f2bf(p);
      if (f32m) __builtin_nontemporal_store(p,  outPf + row * 1024 + c);
      else      __builtin_nontemporal_store(pb, outPs + row * 1024 + c);
      Pb[rloc * 64 + (((g ^ (rloc & 7)) << 3) | cs)] = pb;
    }
  }
  __syncthreads();   // full P now in LDS

  // ---- GEMM2: Q = P @ CB (B = CTX), barrier-free over 16 panels ----
#pragma unroll
  for (int nt = 0; nt < 4; ++nt)
#pragma unroll
    for (int i = 0; i < 16; ++i) acc[nt][i] = 0.0f;

  const short* btb = CTX + (wc * 4) * 32768 + h * 256 + ln * 8;
  const int pbase = (wr * 32 + ln) * 64;   // this wave's 32 P-rows
  for (int kt = 0; kt < 16; ++kt) {
    const short* Pb = &AP[kt * 4096] + pbase;
#pragma unroll
    for (int ks = 0; ks < 4; ++ks) {
      const int ao = ((2 * ks + h) ^ sw) << 3;
      s16x8 a0 = *(const s16x8*)(Pb + ao);
#pragma unroll
      for (int nt = 0; nt < 4; ++nt) {
        s16x8 b = *(const s16x8*)(btb + nt * 32768 + (kt * 4 + ks) * 512);
        acc[nt] = __builtin_amdgcn_mfma_f32_32x32x16_bf16(a0, b, acc[nt], 0, 0, 0);
      }
    }
  }

  // ---- store quantized direct from regs (nontemporal) ----
#pragma unroll
  for (int nt = 0; nt < 4; ++nt) {
    const int c = wc * 128 + nt * 32 + ln;
#pragma unroll
    for (int r = 0; r < 16; ++r) {
      const int row = r0 + wr * 32 + (r & 3) + 8 * (r >> 2) + 4 * h;
      float q = acc[nt][r];
      if (f32m) __builtin_nontemporal_store(q,       outQf + row * 1024 + c);
      else      __builtin_nontemporal_store(f2bf(q), outQs + row * 1024 + c);
    }
  }
}

extern "C" void kernel_launch(void* const* d_in, const int* in_sizes, int n_in,
                              void* d_out, int out_size, void* d_ws, size_t ws_size,
                              hipStream_t stream) {
  short* wss   = (short*)d_ws;
  short* CBhiX = wss;                  // 2 MB
  short* CBloX = wss + (1 << 20);      // 2 MB
  short* CTX   = wss + (2 << 20);      // 2 MB
  int*   flag  = (int*)(wss + (3 << 20));

  k_detect<<<1, 256, 0, stream>>>((const short*)d_in[1], flag);
  k_prep<<<4096, 256, 0, stream>>>(d_in[1], CBhiX, CBloX, CTX, flag);
  k_gvq<<<512, 1024, 0, stream>>>(d_in[0], CBhiX, CBloX, CTX, d_in[2], d_out, flag);
}